// Round 1
// baseline (775.668 us; speedup 1.0000x reference)
//
#include <hip/hip_runtime.h>
#include <hip/hip_bf16.h>
#include <stdint.h>

#define NT 2048
#define DM 1024
#define DFF 2048
#define NE 8
#define NASSIGN (NT*2)
#define CAPROWS (NASSIGN+128)
#define MAXTILES 40
#define BK 32
#define LDT 40   // padded LDS row stride in ushorts (80B): 2-way bank conflicts only

typedef __attribute__((ext_vector_type(4))) float f32x4;
typedef __attribute__((ext_vector_type(8))) short bf16x8;

__device__ __forceinline__ ushort f2bf(float f) {
  union { float f; uint32_t u; } v; v.f = f;
  uint32_t u = v.u;
  return (ushort)((u + 0x7FFFu + ((u >> 16) & 1u)) >> 16);
}
__device__ __forceinline__ float bf2f(ushort h) {
  union { uint32_t u; float f; } v; v.u = ((uint32_t)h) << 16;
  return v.f;
}

// ---------------- router: one wave per token ----------------
__global__ __launch_bounds__(256) void k_router(const float* __restrict__ x,
    const float* __restrict__ rw, int* __restrict__ tok_e, float* __restrict__ tok_p,
    int* __restrict__ cnt1) {
  __shared__ float srw[NE*DM];
  int tid = threadIdx.x;
  #pragma unroll
  for (int i = 0; i < NE*DM/256; i++) srw[tid + i*256] = rw[tid + i*256];
  __syncthreads();
  int lane = tid & 63;
  int t = blockIdx.x*4 + (tid >> 6);
  const float* xr = x + (size_t)t*DM;
  float acc[NE];
  #pragma unroll
  for (int e = 0; e < NE; e++) acc[e] = 0.f;
  for (int i = lane; i < DM; i += 64) {
    float xv = xr[i];
    #pragma unroll
    for (int e = 0; e < NE; e++) acc[e] = fmaf(xv, srw[e*DM + i], acc[e]);
  }
  #pragma unroll
  for (int e = 0; e < NE; e++) {
    float v = acc[e];
    #pragma unroll
    for (int o = 32; o > 0; o >>= 1) v += __shfl_xor(v, o);
    acc[e] = v;
  }
  float mx = acc[0];
  #pragma unroll
  for (int e = 1; e < NE; e++) mx = fmaxf(mx, acc[e]);
  float p[NE]; float s = 0.f;
  #pragma unroll
  for (int e = 0; e < NE; e++) { p[e] = __expf(acc[e]-mx); s += p[e]; }
  int e1 = 0; float b1 = p[0];
  #pragma unroll
  for (int e = 1; e < NE; e++) if (p[e] > b1) { b1 = p[e]; e1 = e; }
  int e2 = -1; float b2 = -1.f;
  #pragma unroll
  for (int e = 0; e < NE; e++) if (e != e1 && p[e] > b2) { b2 = p[e]; e2 = e; }
  if (lane == 0) {
    tok_e[2*t] = e1; tok_e[2*t+1] = e2;
    float inv = 1.f/s;
    tok_p[2*t] = b1*inv; tok_p[2*t+1] = b2*inv;
    atomicAdd(&cnt1[e1], 1); atomicAdd(&cnt1[e2], 1);
  }
}

// ---------------- scan: offsets + tile descriptors ----------------
__global__ void k_scan(const int* __restrict__ cnt1, int* __restrict__ offs,
    int* __restrict__ d_e, int* __restrict__ d_r0, int* __restrict__ d_valid,
    int* __restrict__ ntiles) {
  if (threadIdx.x == 0 && blockIdx.x == 0) {
    int off = 0, nt2 = 0;
    for (int e = 0; e < NE; e++) {
      int c = cnt1[e];
      offs[e] = off;
      for (int r = 0; r < c; r += 128) {
        d_e[nt2] = e; d_r0[nt2] = off + r;
        d_valid[nt2] = (c - r < 128) ? (c - r) : 128;
        nt2++;
      }
      off += c;
    }
    *ntiles = nt2;
  }
}

// ---------------- gather: xg[slot] = bf16(p * x[token]) ----------------
__global__ __launch_bounds__(256) void k_gather(const float* __restrict__ x,
    const int* __restrict__ tok_e, const float* __restrict__ tok_p,
    const int* __restrict__ offs, int* __restrict__ cnt2,
    int* __restrict__ assign_token, ushort* __restrict__ xg) {
  int tid = threadIdx.x, lane = tid & 63;
  int t = blockIdx.x*4 + (tid >> 6);
  const float* xr = x + (size_t)t*DM;
  #pragma unroll
  for (int j = 0; j < 2; j++) {
    int e = tok_e[2*t+j];
    float pp = tok_p[2*t+j];
    int slot = 0;
    if (lane == 0) {
      slot = offs[e] + atomicAdd(&cnt2[e], 1);
      assign_token[slot] = t;
    }
    slot = __shfl(slot, 0);
    ushort* dst = xg + (size_t)slot*DM;
    #pragma unroll
    for (int it = 0; it < 2; it++) {
      int c = lane + it*64;
      float4 v0 = *(const float4*)(xr + c*8);
      float4 v1 = *(const float4*)(xr + c*8 + 4);
      uint4 o;
      o.x = (uint32_t)f2bf(v0.x*pp) | ((uint32_t)f2bf(v0.y*pp) << 16);
      o.y = (uint32_t)f2bf(v0.z*pp) | ((uint32_t)f2bf(v0.w*pp) << 16);
      o.z = (uint32_t)f2bf(v1.x*pp) | ((uint32_t)f2bf(v1.y*pp) << 16);
      o.w = (uint32_t)f2bf(v1.z*pp) | ((uint32_t)f2bf(v1.w*pp) << 16);
      *(uint4*)(dst + c*8) = o;
    }
  }
}

// ---------------- transpose: src [E][K][N] f32 -> dst [E][N][K] bf16 ----------------
__global__ __launch_bounds__(256) void k_transpose(const float* __restrict__ src,
    ushort* __restrict__ dst, int K, int N) {
  __shared__ ushort tl[64][68];
  int e = blockIdx.z;
  const float* s = src + (size_t)e*K*N;
  ushort* d = dst + (size_t)e*N*K;
  int n0 = blockIdx.x*64, k0 = blockIdx.y*64;
  int tid = threadIdx.x;
  int cx = tid & 15, ry = tid >> 4;
  #pragma unroll
  for (int p = 0; p < 4; p++) {
    int k = k0 + ry + p*16;
    float4 v = *(const float4*)(s + (size_t)k*N + n0 + cx*4);
    tl[cx*4+0][ry+p*16] = f2bf(v.x);
    tl[cx*4+1][ry+p*16] = f2bf(v.y);
    tl[cx*4+2][ry+p*16] = f2bf(v.z);
    tl[cx*4+3][ry+p*16] = f2bf(v.w);
  }
  __syncthreads();
  #pragma unroll
  for (int p = 0; p < 4; p++) {
    int n = ry + p*16;
    ushort* dp = d + (size_t)(n0+n)*K + k0 + cx*4;
    uint2 o;
    o.x = (uint32_t)tl[n][cx*4+0] | ((uint32_t)tl[n][cx*4+1] << 16);
    o.y = (uint32_t)tl[n][cx*4+2] | ((uint32_t)tl[n][cx*4+3] << 16);
    *(uint2*)dp = o;
  }
}

// ---------------- GEMM: 128x128 tile, BK=32, 4 waves (2x2), reg-prefetch staging ----
// MODE 0: C = xg @ gu_t[gate cols] ; write silu(clip(C)) bf16 -> hidden
// MODE 1: C = xg @ gu_t[up cols]   ; hidden *= C (in place)
// MODE 2: C = hidden @ dn_t        ; atomicAdd into out[token]
template<int MODE>
__global__ __launch_bounds__(256) void k_gemm(
    const ushort* __restrict__ Abuf, const ushort* __restrict__ Bbuf,
    ushort* __restrict__ hidden, float* __restrict__ out,
    const int* __restrict__ d_e, const int* __restrict__ d_r0,
    const int* __restrict__ d_valid, const int* __restrict__ ntiles,
    const int* __restrict__ assign_token) {
  if (blockIdx.y >= *ntiles) return;
  const int K = (MODE == 2) ? DFF : DM;
  const int e    = d_e[blockIdx.y];
  const int row0 = d_r0[blockIdx.y];
  const int valid = d_valid[blockIdx.y];
  const int n0 = blockIdx.x * 128;

  __shared__ __align__(16) ushort As[128*LDT];
  __shared__ __align__(16) ushort Bs[128*LDT];
  __shared__ int toks[128];

  int tid = threadIdx.x;
  int lane = tid & 63;
  int wv = tid >> 6;
  int wm = wv >> 1, wn = wv & 1;

  const ushort* Ab = Abuf + (size_t)row0 * K;
  const ushort* Bb;
  if (MODE == 0)      Bb = Bbuf + ((size_t)e*4096 + n0) * DM;
  else if (MODE == 1) Bb = Bbuf + ((size_t)e*4096 + 2048 + n0) * DM;
  else                Bb = Bbuf + ((size_t)e*1024 + n0) * DFF;

  if (MODE == 2 && tid < 128) toks[tid] = assign_token[row0 + tid];

  // staging map: thread -> row = tid>>1 (0..127), 32B chunk at k-offset (tid&1)*16
  int srow = tid >> 1;
  int skc  = (tid & 1) * 16;
  const ushort* Ald = Ab + (size_t)srow*K + skc;
  const ushort* Bld = Bb + (size_t)srow*K + skc;
  ushort* Ast = As + srow*LDT + skc;
  ushort* Bst = Bs + srow*LDT + skc;

  uint4 pa0 = *(const uint4*)(Ald);
  uint4 pa1 = *(const uint4*)(Ald + 8);
  uint4 pb0 = *(const uint4*)(Bld);
  uint4 pb1 = *(const uint4*)(Bld + 8);

  f32x4 acc[4][4];
  f32x4 zz = {0.f, 0.f, 0.f, 0.f};
  #pragma unroll
  for (int mi = 0; mi < 4; mi++)
    #pragma unroll
    for (int ni = 0; ni < 4; ni++) acc[mi][ni] = zz;

  const int NK = K / BK;
  for (int kt = 0; kt < NK; kt++) {
    __syncthreads();
    *(uint4*)(Ast)     = pa0; *(uint4*)(Ast + 8) = pa1;
    *(uint4*)(Bst)     = pb0; *(uint4*)(Bst + 8) = pb1;
    __syncthreads();
    if (kt + 1 < NK) {
      const ushort* an = Ald + (kt+1)*BK;
      const ushort* bn = Bld + (kt+1)*BK;
      pa0 = *(const uint4*)(an); pa1 = *(const uint4*)(an + 8);
      pb0 = *(const uint4*)(bn); pb1 = *(const uint4*)(bn + 8);
    }
    bf16x8 af[4], bfr[4];
    int ko = (lane >> 4) * 8;
    #pragma unroll
    for (int mi = 0; mi < 4; mi++)
      af[mi] = *(const bf16x8*)(As + (wm*64 + mi*16 + (lane&15))*LDT + ko);
    #pragma unroll
    for (int ni = 0; ni < 4; ni++)
      bfr[ni] = *(const bf16x8*)(Bs + (wn*64 + ni*16 + (lane&15))*LDT + ko);
    #pragma unroll
    for (int mi = 0; mi < 4; mi++)
      #pragma unroll
      for (int ni = 0; ni < 4; ni++)
        acc[mi][ni] = __builtin_amdgcn_mfma_f32_16x16x32_bf16(af[mi], bfr[ni], acc[mi][ni], 0, 0, 0);
  }

  #pragma unroll
  for (int mi = 0; mi < 4; mi++) {
    #pragma unroll
    for (int r = 0; r < 4; r++) {
      int row_l = wm*64 + mi*16 + (lane>>4)*4 + r;
      if (row_l < valid) {
        #pragma unroll
        for (int ni = 0; ni < 4; ni++) {
          int col = n0 + wn*64 + ni*16 + (lane&15);
          float v = acc[mi][ni][r];
          if (MODE == 0) {
            float g = fminf(fmaxf(v, -10.f), 10.f);
            float sg = g / (1.f + __expf(-g));
            hidden[(size_t)(row0+row_l)*DFF + col] = f2bf(sg);
          } else if (MODE == 1) {
            size_t idx = (size_t)(row0+row_l)*DFF + col;
            hidden[idx] = f2bf(bf2f(hidden[idx]) * v);
          } else {
            atomicAdd(out + (size_t)toks[row_l]*DM + col, v);
          }
        }
      }
    }
  }
}

// ---------------- launch ----------------
extern "C" void kernel_launch(void* const* d_in, const int* in_sizes, int n_in,
                              void* d_out, int out_size, void* d_ws, size_t ws_size,
                              hipStream_t stream) {
  const float* x   = (const float*)d_in[0];
  const float* rw  = (const float*)d_in[1];
  const float* guw = (const float*)d_in[2];
  const float* dnw = (const float*)d_in[3];
  float* out = (float*)d_out;
  char* ws = (char*)d_ws;

  int* ctrl = (int*)ws;
  int* cnt1 = ctrl;           // 8 ints
  int* cnt2 = ctrl + 8;       // 8 ints
  int* ntl  = ctrl + 16;
  int* offs = ctrl + 24;      // 8
  int* de   = ctrl + 32;      // 64
  int* dr0  = ctrl + 96;      // 64
  int* dva  = ctrl + 160;     // 64

  int*    tok_e  = (int*)  (ws + 4096);
  float*  tok_p  = (float*)(ws + 20480);
  int*    assign = (int*)  (ws + 36864);
  ushort* xg     = (ushort*)(ws + 53760);                       // CAPROWS x 1024 bf16
  ushort* hid    = (ushort*)(ws + 8704512ull);                  // CAPROWS x 2048 bf16
  ushort* gut    = (ushort*)(ws + 26006016ull);                 // 8 x 4096 x 1024 bf16
  ushort* dnt    = (ushort*)(ws + 93114880ull);                 // 8 x 1024 x 2048 bf16
  // total ws needed: 126,669,312 bytes

  hipMemsetAsync(cnt1, 0, 64, stream);
  hipMemsetAsync(out, 0, (size_t)NT*DM*4, stream);

  k_router<<<NT/4, 256, 0, stream>>>(x, rw, tok_e, tok_p, cnt1);
  k_scan<<<1, 64, 0, stream>>>(cnt1, offs, de, dr0, dva, ntl);
  k_gather<<<NT/4, 256, 0, stream>>>(x, tok_e, tok_p, offs, cnt2, assign, xg);
  k_transpose<<<dim3(64, 16, 8), 256, 0, stream>>>(guw, gut, 1024, 4096);
  k_transpose<<<dim3(16, 32, 8), 256, 0, stream>>>(dnw, dnt, 2048, 1024);

  k_gemm<0><<<dim3(16, MAXTILES), 256, 0, stream>>>(xg, gut, hid, out, de, dr0, dva, ntl, assign);
  k_gemm<1><<<dim3(16, MAXTILES), 256, 0, stream>>>(xg, gut, hid, out, de, dr0, dva, ntl, assign);
  k_gemm<2><<<dim3(8,  MAXTILES), 256, 0, stream>>>(hid, dnt, hid, out, de, dr0, dva, ntl, assign);
}

// Round 2
// 438.218 us; speedup vs baseline: 1.7700x; 1.7700x over previous
//
#include <hip/hip_runtime.h>
#include <hip/hip_bf16.h>
#include <stdint.h>

#define NT 2048
#define DM 1024
#define DFF 2048
#define NE 8
#define NASSIGN (NT*2)
#define CAPROWS (NASSIGN+128)
#define MAXTILES 40
#define BK 32
#define LDT 40   // padded LDS row stride in ushorts (80B): 2-way bank conflicts only

typedef __attribute__((ext_vector_type(4))) float f32x4;
typedef __attribute__((ext_vector_type(8))) short bf16x8;

__device__ __forceinline__ ushort f2bf(float f) {
  union { float f; uint32_t u; } v; v.f = f;
  uint32_t u = v.u;
  return (ushort)((u + 0x7FFFu + ((u >> 16) & 1u)) >> 16);
}
__device__ __forceinline__ float bf2f(ushort h) {
  union { uint32_t u; float f; } v; v.u = ((uint32_t)h) << 16;
  return v.f;
}

// ---------------- router: one wave per token (no atomics) ----------------
__global__ __launch_bounds__(256) void k_router(const float* __restrict__ x,
    const float* __restrict__ rw, int* __restrict__ tok_e, float* __restrict__ tok_p) {
  __shared__ float srw[NE*DM];
  int tid = threadIdx.x;
  #pragma unroll
  for (int i = 0; i < NE*DM/256; i++) srw[tid + i*256] = rw[tid + i*256];
  __syncthreads();
  int lane = tid & 63;
  int t = blockIdx.x*4 + (tid >> 6);
  const float* xr = x + (size_t)t*DM;
  float acc[NE];
  #pragma unroll
  for (int e = 0; e < NE; e++) acc[e] = 0.f;
  for (int i = lane; i < DM; i += 64) {
    float xv = xr[i];
    #pragma unroll
    for (int e = 0; e < NE; e++) acc[e] = fmaf(xv, srw[e*DM + i], acc[e]);
  }
  #pragma unroll
  for (int e = 0; e < NE; e++) {
    float v = acc[e];
    #pragma unroll
    for (int o = 32; o > 0; o >>= 1) v += __shfl_xor(v, o);
    acc[e] = v;
  }
  float mx = acc[0];
  #pragma unroll
  for (int e = 1; e < NE; e++) mx = fmaxf(mx, acc[e]);
  float p[NE]; float s = 0.f;
  #pragma unroll
  for (int e = 0; e < NE; e++) { p[e] = __expf(acc[e]-mx); s += p[e]; }
  int e1 = 0; float b1 = p[0];
  #pragma unroll
  for (int e = 1; e < NE; e++) if (p[e] > b1) { b1 = p[e]; e1 = e; }
  int e2 = -1; float b2 = -1.f;
  #pragma unroll
  for (int e = 0; e < NE; e++) if (e != e1 && p[e] > b2) { b2 = p[e]; e2 = e; }
  if (lane == 0) {
    tok_e[2*t] = e1; tok_e[2*t+1] = e2;
    float inv = 1.f/s;
    tok_p[2*t] = b1*inv; tok_p[2*t+1] = b2*inv;
  }
}

// ---------------- count: deterministic within-chunk ranks, no atomics -------
// chunk = 256 tokens. rank(t,j) = #{(t',j') in chunk: e'==e, (t',j')<(t,j)}.
__global__ __launch_bounds__(256) void k_count(const int* __restrict__ tok_e,
    int* __restrict__ rnk, int* __restrict__ chunk_cnt) {
  __shared__ int wcnt[4][NE];
  __shared__ int woff[4][NE];
  int tid = threadIdx.x, lane = tid & 63, wv = tid >> 6;
  int t = blockIdx.x*256 + tid;
  int e1 = tok_e[2*t], e2 = tok_e[2*t+1];
  unsigned long long lt = (lane == 63) ? 0x7FFFFFFFFFFFFFFFull
                                       : ((1ull << lane) - 1ull);
  int r0 = 0, r1 = 0;
  #pragma unroll
  for (int e = 0; e < NE; e++) {
    unsigned long long m0 = __ballot(e1 == e);
    unsigned long long m1 = __ballot(e2 == e);
    if (e1 == e) r0 = __popcll(m0 & lt) + __popcll(m1 & lt);
    if (e2 == e) r1 = __popcll(m0 & lt) + (int)(e1 == e) + __popcll(m1 & lt);
    if (lane == 0) wcnt[wv][e] = __popcll(m0) + __popcll(m1);
  }
  __syncthreads();
  if (tid < NE) {
    int s = 0;
    #pragma unroll
    for (int w = 0; w < 4; w++) { woff[w][tid] = s; s += wcnt[w][tid]; }
    chunk_cnt[blockIdx.x*NE + tid] = s;
  }
  __syncthreads();
  rnk[2*t]   = woff[wv][e1] + r0;
  rnk[2*t+1] = woff[wv][e2] + r1;
}

// ---------------- scan: expert offsets, chunk offsets, tile descriptors -----
__global__ void k_scan(const int* __restrict__ chunk_cnt, int* __restrict__ offs,
    int* __restrict__ coff, int* __restrict__ d_e, int* __restrict__ d_r0,
    int* __restrict__ d_valid, int* __restrict__ ntiles) {
  if (threadIdx.x == 0 && blockIdx.x == 0) {
    int cnt[NE];
    for (int e = 0; e < NE; e++) {
      int s = 0;
      for (int c = 0; c < 8; c++) s += chunk_cnt[c*NE + e];
      cnt[e] = s;
    }
    int off = 0, nt2 = 0;
    for (int e = 0; e < NE; e++) {
      offs[e] = off;
      int s = off;
      for (int c = 0; c < 8; c++) { coff[c*NE + e] = s; s += chunk_cnt[c*NE + e]; }
      for (int r = 0; r < cnt[e]; r += 128) {
        d_e[nt2] = e; d_r0[nt2] = off + r;
        d_valid[nt2] = (cnt[e] - r < 128) ? (cnt[e] - r) : 128;
        nt2++;
      }
      off += cnt[e];
    }
    *ntiles = nt2;
  }
}

// ---------------- gather: xg[slot] = bf16(p * x[token]), no atomics ---------
__global__ __launch_bounds__(256) void k_gather(const float* __restrict__ x,
    const int* __restrict__ tok_e, const float* __restrict__ tok_p,
    const int* __restrict__ rnk, const int* __restrict__ coff,
    int* __restrict__ assign_token, ushort* __restrict__ xg) {
  int tid = threadIdx.x, lane = tid & 63;
  int t = blockIdx.x*4 + (tid >> 6);
  const float* xr = x + (size_t)t*DM;
  int chunk = t >> 8;
  #pragma unroll
  for (int j = 0; j < 2; j++) {
    int e = tok_e[2*t+j];
    float pp = tok_p[2*t+j];
    int slot = coff[chunk*NE + e] + rnk[2*t+j];
    if (lane == 0) assign_token[slot] = t;
    ushort* dst = xg + (size_t)slot*DM;
    #pragma unroll
    for (int it = 0; it < 2; it++) {
      int c = lane + it*64;
      float4 v0 = *(const float4*)(xr + c*8);
      float4 v1 = *(const float4*)(xr + c*8 + 4);
      uint4 o;
      o.x = (uint32_t)f2bf(v0.x*pp) | ((uint32_t)f2bf(v0.y*pp) << 16);
      o.y = (uint32_t)f2bf(v0.z*pp) | ((uint32_t)f2bf(v0.w*pp) << 16);
      o.z = (uint32_t)f2bf(v1.x*pp) | ((uint32_t)f2bf(v1.y*pp) << 16);
      o.w = (uint32_t)f2bf(v1.z*pp) | ((uint32_t)f2bf(v1.w*pp) << 16);
      *(uint4*)(dst + c*8) = o;
    }
  }
}

// ---------------- transpose: src [E][K][N] f32 -> dst [E][N][K] bf16 --------
__global__ __launch_bounds__(256) void k_transpose(const float* __restrict__ src,
    ushort* __restrict__ dst, int K, int N) {
  __shared__ ushort tl[64][68];
  int e = blockIdx.z;
  const float* s = src + (size_t)e*K*N;
  ushort* d = dst + (size_t)e*N*K;
  int n0 = blockIdx.x*64, k0 = blockIdx.y*64;
  int tid = threadIdx.x;
  int cx = tid & 15, ry = tid >> 4;
  #pragma unroll
  for (int p = 0; p < 4; p++) {
    int k = k0 + ry + p*16;
    float4 v = *(const float4*)(s + (size_t)k*N + n0 + cx*4);
    tl[cx*4+0][ry+p*16] = f2bf(v.x);
    tl[cx*4+1][ry+p*16] = f2bf(v.y);
    tl[cx*4+2][ry+p*16] = f2bf(v.z);
    tl[cx*4+3][ry+p*16] = f2bf(v.w);
  }
  __syncthreads();
  #pragma unroll
  for (int p = 0; p < 4; p++) {
    int n = ry + p*16;
    ushort* dp = d + (size_t)(n0+n)*K + k0 + cx*4;
    uint2 o;
    o.x = (uint32_t)tl[n][cx*4+0] | ((uint32_t)tl[n][cx*4+1] << 16);
    o.y = (uint32_t)tl[n][cx*4+2] | ((uint32_t)tl[n][cx*4+3] << 16);
    *(uint2*)dp = o;
  }
}

// ---------------- GEMM: 128x128 tile, BK=32, 4 waves (2x2), reg-prefetch ----
// MODE 0: C = xg @ gu_t[gate cols] ; write silu(clip(C)) bf16 -> hidden
// MODE 1: C = xg @ gu_t[up cols]   ; hidden *= C (in place)
// MODE 2: C = hidden @ dn_t        ; atomicAdd into out[token]
template<int MODE>
__global__ __launch_bounds__(256) void k_gemm(
    const ushort* __restrict__ Abuf, const ushort* __restrict__ Bbuf,
    ushort* __restrict__ hidden, float* __restrict__ out,
    const int* __restrict__ d_e, const int* __restrict__ d_r0,
    const int* __restrict__ d_valid, const int* __restrict__ ntiles,
    const int* __restrict__ assign_token) {
  if (blockIdx.y >= *ntiles) return;
  const int K = (MODE == 2) ? DFF : DM;
  const int e    = d_e[blockIdx.y];
  const int row0 = d_r0[blockIdx.y];
  const int valid = d_valid[blockIdx.y];
  const int n0 = blockIdx.x * 128;

  __shared__ __align__(16) ushort As[128*LDT];
  __shared__ __align__(16) ushort Bs[128*LDT];
  __shared__ int toks[128];

  int tid = threadIdx.x;
  int lane = tid & 63;
  int wv = tid >> 6;
  int wm = wv >> 1, wn = wv & 1;

  const ushort* Ab = Abuf + (size_t)row0 * K;
  const ushort* Bb;
  if (MODE == 0)      Bb = Bbuf + ((size_t)e*4096 + n0) * DM;
  else if (MODE == 1) Bb = Bbuf + ((size_t)e*4096 + 2048 + n0) * DM;
  else                Bb = Bbuf + ((size_t)e*1024 + n0) * DFF;

  if (MODE == 2 && tid < 128) toks[tid] = assign_token[row0 + tid];

  int srow = tid >> 1;
  int skc  = (tid & 1) * 16;
  const ushort* Ald = Ab + (size_t)srow*K + skc;
  const ushort* Bld = Bb + (size_t)srow*K + skc;
  ushort* Ast = As + srow*LDT + skc;
  ushort* Bst = Bs + srow*LDT + skc;

  uint4 pa0 = *(const uint4*)(Ald);
  uint4 pa1 = *(const uint4*)(Ald + 8);
  uint4 pb0 = *(const uint4*)(Bld);
  uint4 pb1 = *(const uint4*)(Bld + 8);

  f32x4 acc[4][4];
  f32x4 zz = {0.f, 0.f, 0.f, 0.f};
  #pragma unroll
  for (int mi = 0; mi < 4; mi++)
    #pragma unroll
    for (int ni = 0; ni < 4; ni++) acc[mi][ni] = zz;

  const int NK = K / BK;
  for (int kt = 0; kt < NK; kt++) {
    __syncthreads();
    *(uint4*)(Ast)     = pa0; *(uint4*)(Ast + 8) = pa1;
    *(uint4*)(Bst)     = pb0; *(uint4*)(Bst + 8) = pb1;
    __syncthreads();
    if (kt + 1 < NK) {
      const ushort* an = Ald + (kt+1)*BK;
      const ushort* bn = Bld + (kt+1)*BK;
      pa0 = *(const uint4*)(an); pa1 = *(const uint4*)(an + 8);
      pb0 = *(const uint4*)(bn); pb1 = *(const uint4*)(bn + 8);
    }
    bf16x8 af[4], bfr[4];
    int ko = (lane >> 4) * 8;
    #pragma unroll
    for (int mi = 0; mi < 4; mi++)
      af[mi] = *(const bf16x8*)(As + (wm*64 + mi*16 + (lane&15))*LDT + ko);
    #pragma unroll
    for (int ni = 0; ni < 4; ni++)
      bfr[ni] = *(const bf16x8*)(Bs + (wn*64 + ni*16 + (lane&15))*LDT + ko);
    #pragma unroll
    for (int mi = 0; mi < 4; mi++)
      #pragma unroll
      for (int ni = 0; ni < 4; ni++)
        acc[mi][ni] = __builtin_amdgcn_mfma_f32_16x16x32_bf16(af[mi], bfr[ni], acc[mi][ni], 0, 0, 0);
  }

  #pragma unroll
  for (int mi = 0; mi < 4; mi++) {
    #pragma unroll
    for (int r = 0; r < 4; r++) {
      int row_l = wm*64 + mi*16 + (lane>>4)*4 + r;
      if (row_l < valid) {
        #pragma unroll
        for (int ni = 0; ni < 4; ni++) {
          int col = n0 + wn*64 + ni*16 + (lane&15);
          float v = acc[mi][ni][r];
          if (MODE == 0) {
            float g = fminf(fmaxf(v, -10.f), 10.f);
            float sg = g / (1.f + __expf(-g));
            hidden[(size_t)(row0+row_l)*DFF + col] = f2bf(sg);
          } else if (MODE == 1) {
            size_t idx = (size_t)(row0+row_l)*DFF + col;
            hidden[idx] = f2bf(bf2f(hidden[idx]) * v);
          } else {
            atomicAdd(out + (size_t)toks[row_l]*DM + col, v);
          }
        }
      }
    }
  }
}

// ---------------- launch ----------------
extern "C" void kernel_launch(void* const* d_in, const int* in_sizes, int n_in,
                              void* d_out, int out_size, void* d_ws, size_t ws_size,
                              hipStream_t stream) {
  const float* x   = (const float*)d_in[0];
  const float* rw  = (const float*)d_in[1];
  const float* guw = (const float*)d_in[2];
  const float* dnw = (const float*)d_in[3];
  float* out = (float*)d_out;
  char* ws = (char*)d_ws;

  int* ctrl = (int*)ws;        // 2 KB control block
  int* ntl  = ctrl + 0;        // 1
  int* offs = ctrl + 8;        // 8
  int* de   = ctrl + 16;       // 64
  int* dr0  = ctrl + 80;       // 64
  int* dva  = ctrl + 144;      // 64
  int* ccnt = ctrl + 208;      // 64 chunk_cnt[8][8]
  int* coff = ctrl + 272;      // 64 coff[8][8]

  int*    tok_e  = (int*)  (ws + 2048);          // 4096 ints
  float*  tok_p  = (float*)(ws + 18432);         // 4096 f32
  int*    assign = (int*)  (ws + 34816);         // 4096 ints
  ushort* xg     = (ushort*)(ws + 51200);        // CAPROWS x 1024 bf16
  ushort* hid    = (ushort*)(ws + 8701952ull);   // CAPROWS x 2048 bf16
  int*    rnk    = (int*)   (ws + 8701952ull);   // aliases hid head: dead before gemm<0>
  ushort* gut    = (ushort*)(ws + 26003456ull);  // 8 x 4096 x 1024 bf16
  ushort* dnt    = (ushort*)(ws + 93112320ull);  // 8 x 1024 x 2048 bf16
  // total ws needed: 126,666,752 bytes (<= proven 126,669,312)

  hipMemsetAsync(out, 0, (size_t)NT*DM*4, stream);

  k_router<<<NT/4, 256, 0, stream>>>(x, rw, tok_e, tok_p);
  k_count<<<NT/256, 256, 0, stream>>>(tok_e, rnk, ccnt);
  k_scan<<<1, 64, 0, stream>>>(ccnt, offs, coff, de, dr0, dva, ntl);
  k_gather<<<NT/4, 256, 0, stream>>>(x, tok_e, tok_p, rnk, coff, assign, xg);
  k_transpose<<<dim3(64, 16, 8), 256, 0, stream>>>(guw, gut, 1024, 4096);
  k_transpose<<<dim3(16, 32, 8), 256, 0, stream>>>(dnw, dnt, 2048, 1024);

  k_gemm<0><<<dim3(16, MAXTILES), 256, 0, stream>>>(xg, gut, hid, out, de, dr0, dva, ntl, assign);
  k_gemm<1><<<dim3(16, MAXTILES), 256, 0, stream>>>(xg, gut, hid, out, de, dr0, dva, ntl, assign);
  k_gemm<2><<<dim3(8,  MAXTILES), 256, 0, stream>>>(hid, dnt, hid, out, de, dr0, dva, ntl, assign);
}